// Round 2
// baseline (198.579 us; speedup 1.0000x reference)
//
#include <hip/hip_runtime.h>
#include <math.h>

typedef __attribute__((ext_vector_type(8))) short short8;
typedef __attribute__((ext_vector_type(4))) float f32x4;
typedef __attribute__((ext_vector_type(16))) float f32x16;

#define NTAP 125
#define DCH 32

static __device__ __forceinline__ unsigned short f2bf(float f) {
    union { float f; unsigned u; } v; v.f = f;
    unsigned u = v.u;
    return (unsigned short)((u + 0x7FFFu + ((u >> 16) & 1u)) >> 16);
}

static __device__ __forceinline__ void gld_lds16(const void* g, void* l) {
    __builtin_amdgcn_global_load_lds(
        (const __attribute__((address_space(1))) unsigned int*)g,
        (__attribute__((address_space(3))) unsigned int*)l, 16, 0, 0);
}

// ---------------------------------------------------------------------------
// Kernel 1: build conv weights kw[ci=32][tap=125][co=32] (fp32).
// Skip connection folded into center tap 62. (verified R0-R3)
// ---------------------------------------------------------------------------
__global__ __launch_bounds__(128) void build_kern(
    const float* __restrict__ weight,
    const float* __restrict__ w_sc0,
    const float* __restrict__ w_sc1,
    float* __restrict__ kw)
{
    const int t = blockIdx.x;
    const int dx = t / 25, dy = (t / 5) % 5, dz = t % 5;
    const float px = dx - 2.0f, py = dy - 2.0f, pz = dz - 2.0f;
    const float d = sqrtf(px * px + py * py + pz * pz);

    const float stepv = 2.5f / 6.0f;
    const float embc = 1.14136f * expf(2.0f);
    float emb[5];
#pragma unroll
    for (int n = 0; n < 5; ++n) {
        float diff = (d - stepv * (float)(n + 1)) / stepv;
        float a = diff + 1.0f, bb = 1.0f - diff;
        float v = 0.0f;
        if (a > 0.0f && bb > 0.0f)
            v = embc * expf(-1.0f / a) * expf(-1.0f / bb);
        emb[n] = v;
    }

    const float inv_d = (d > 0.0f) ? 1.0f / d : 0.0f;
    const float ux = px * inv_d, uy = py * inv_d, uz = pz * inv_d;
    const float s3 = 1.73205081f, s5 = 2.23606798f, s15 = 3.87298335f;
    float sh[9];
    sh[0] = 1.0f;
    sh[1] = s3 * ux; sh[2] = s3 * uy; sh[3] = s3 * uz;
    sh[4] = s15 * ux * uz;
    sh[5] = s15 * ux * uy;
    sh[6] = s5 * (uy * uy - 0.5f * (ux * ux + uz * uz));
    sh[7] = s15 * uy * uz;
    sh[8] = 0.5f * s15 * (uz * uz - ux * ux);

    const float i_s2 = 0.70710678f, i_s6 = 0.40824829f, i_s5 = 0.44721360f;
    float T[3][3];
    T[0][0] = i_s5 * (-sh[6] * i_s6 - sh[8] * i_s2);
    T[0][1] = i_s5 * (sh[5] * i_s2);
    T[0][2] = i_s5 * (sh[4] * i_s2);
    T[1][0] = T[0][1];
    T[1][1] = i_s5 * (2.0f * sh[6] * i_s6);
    T[1][2] = i_s5 * (sh[7] * i_s2);
    T[2][0] = T[0][2];
    T[2][1] = T[1][2];
    T[2][2] = i_s5 * (-sh[6] * i_s6 + sh[8] * i_s2);

    __shared__ float Wt[320];
    for (int col = threadIdx.x; col < 320; col += 128) {
        float a = 0.0f;
#pragma unroll
        for (int n = 0; n < 5; ++n) a += emb[n] * weight[n * 320 + col];
        Wt[col] = a * (1.0f / 125.0f);
    }
    __syncthreads();

    const float pw0 = 0.25f;
    const float pw1 = 0.35355339f;
    const float inv_s3 = 0.57735027f;
    const float inv_s8 = 0.35355339f;

    for (int idx = threadIdx.x; idx < 1024; idx += 128) {
        const int o = idx >> 5, i = idx & 31;
        float val;
        if (o < 8) {
            if (i < 8) {
                val = pw0 * Wt[i * 8 + o];
            } else {
                const int u = (i - 8) / 3, m = (i - 8) % 3;
                val = pw0 * inv_s3 * Wt[192 + u * 8 + o] * sh[1 + m];
            }
        } else {
            const int v = (o - 8) / 3, k = (o - 8) % 3;
            if (i < 8) {
                val = pw1 * inv_s3 * Wt[64 + i * 8 + v] * sh[1 + k];
            } else {
                const int u = (i - 8) / 3, m = (i - 8) % 3;
                float tv = Wt[256 + u * 8 + v] * T[m][k];
                if (m == k) tv += inv_s3 * Wt[128 + u * 8 + v];
                val = pw1 * tv;
            }
        }
        if (t == 62) {
            if (o < 8 && i < 8) {
                val += inv_s8 * w_sc0[i * 8 + o];
            } else if (o >= 8 && i >= 8) {
                const int u = (i - 8) / 3, m = (i - 8) % 3;
                const int v = (o - 8) / 3, k = (o - 8) % 3;
                if (m == k) val += inv_s8 * w_sc1[u * 8 + v];
            }
        }
        kw[(i * NTAP + t) * DCH + o] = val;
    }
}

// ---------------------------------------------------------------------------
// Kernel 2: pack kw -> bf16 B-fragments for mfma_f32_32x32x16_bf16.
// kwb[tap][kh][lane][8]: lane l holds B[k=(l>>5)*8+j][n=l&31],
// ci = kh*16 + (l>>5)*8 + j, co = l&31.
// ---------------------------------------------------------------------------
__global__ __launch_bounds__(128) void pack_b(
    const float* __restrict__ kw, unsigned short* __restrict__ kwb)
{
    const int t = blockIdx.x;
    const int tid = threadIdx.x;
    const int kh = tid >> 6, l = tid & 63;
    const int co = l & 31;
    const int cib = kh * 16 + (l >> 5) * 8;
    unsigned short v[8];
#pragma unroll
    for (int j = 0; j < 8; ++j)
        v[j] = f2bf(kw[((cib + j) * NTAP + t) * DCH + co]);
    uint4 o;
    o.x = (unsigned)v[0] | ((unsigned)v[1] << 16);
    o.y = (unsigned)v[2] | ((unsigned)v[3] << 16);
    o.z = (unsigned)v[4] | ((unsigned)v[5] << 16);
    o.w = (unsigned)v[6] | ((unsigned)v[7] << 16);
    *reinterpret_cast<uint4*>(kwb + ((size_t)(t * 2 + kh) * 64 + l) * 8) = o;
}

// ---------------------------------------------------------------------------
// Kernel 3: transpose x fp32 [b][ci][X][Y][Z] -> bf16 x_t[b][X][Y][Z][ci=32]
// ---------------------------------------------------------------------------
__global__ __launch_bounds__(256) void xpose(
    const float* __restrict__ x, unsigned short* __restrict__ xt)
{
    const int xx = blockIdx.x, yy = blockIdx.y, b = blockIdx.z;
    const int t = threadIdx.x;
    const int z = t & 63, part = t >> 6;
    const float* src = x + ((((size_t)b * 32) * 64 + xx) * 64 + yy) * 64 + z;
    unsigned short v[8];
#pragma unroll
    for (int j = 0; j < 8; ++j)
        v[j] = f2bf(src[(size_t)(part * 8 + j) * 262144]);
    uint4 o;
    o.x = (unsigned)v[0] | ((unsigned)v[1] << 16);
    o.y = (unsigned)v[2] | ((unsigned)v[3] << 16);
    o.z = (unsigned)v[4] | ((unsigned)v[5] << 16);
    o.w = (unsigned)v[6] | ((unsigned)v[7] << 16);
    *reinterpret_cast<uint4*>(
        xt + ((((size_t)b * 64 + xx) * 64 + yy) * 64 + z) * 32 + part * 8) = o;
}

__global__ void zero_fill(float4* p) {
    p[threadIdx.x] = make_float4(0.f, 0.f, 0.f, 0.f);
}

// ---------------------------------------------------------------------------
// Kernel 4: implicit-GEMM conv via mfma_f32_32x32x16_bf16.
// Block 256 thr (4 waves), tile 4x*4y*64z, all 32 co. Grid 16*16*2 = 512
// blocks = 2/CU. Wave wv: zh = wv&1, oy pair = (wv>>1)*2 + {0,1}; 8 acc
// (4 ox x 2 oy) per wave -> 0.9 ds_read/MFMA.
// LDS 68608 B: Bs[25 tap][2 kh][64][16B] (51200) + slab[4 row][68 slot][4
// chunk][16B] (17408). Swizzle: chunk ^= (slot>>1)&3 (R1, conflict-fixed).
// R2: T14 async-STAGE split for the slab. Slab staging is reg-based:
// issue next step's global_load_dwordx4 BEFORE compute of current step,
// ds_write after the barrier. Raw s_barrier + manual lgkmcnt(0) replaces
// __syncthreads -> NO vmcnt(0) drain per step (that drain was ~2.5k
// cyc/step = the 40%-MfmaUtil ceiling). Bs stays global_load_lds (once per
// dy) covered by a COUNTED vmcnt(K): K = this wave's in-flight slab
// prefetch loads (wave0:5, waves1-3:4), so the wait retires exactly the
// older Bs loads.
// ---------------------------------------------------------------------------
__global__ __launch_bounds__(256, 2) void conv_mfma(
    const unsigned short* __restrict__ xt,   // [b][64][64][64][32] bf16
    const unsigned short* __restrict__ kwb,  // [125][2][64][8]
    const unsigned short* __restrict__ zpage,
    float* __restrict__ out)                 // [b][32][64][64][64]
{
    extern __shared__ unsigned short smem[];
    char* lds = (char*)smem;

    const int tid = threadIdx.x;
    const int lane = tid & 63;
    const int wv = tid >> 6;                 // 0..3
    const int oyp = wv >> 1, zh = wv & 1;    // oy pair, z half
    const int x0 = blockIdx.x * 4, y0 = blockIdx.y * 4;
    const int b = blockIdx.z;
    const int l31 = lane & 31, hi = lane >> 5;

    // A-read base addresses (slab) for oyi=0; oyi=1 adds 68*64 = 4352.
    int abase[5][2];
#pragma unroll
    for (int dz = 0; dz < 5; ++dz) {
        const int s = zh * 32 + l31 + dz;
#pragma unroll
        for (int kh = 0; kh < 2; ++kh) {
            const int cph = (kh * 2 + hi) ^ ((s >> 1) & 3);
            abase[dz][kh] = 51200 + (((((oyp * 2) * 68 + s) << 2) | cph) << 4);
        }
    }
    const int bbase = lane * 16;

    // slab per-thread chunk precompute: chunk c = tid + p*256 (p<4 always
    // valid; p==4 only for tid<64 -> wave0 has 5 loads, waves1-3 have 4).
    int srow[5]; int soff[5]; bool szok[5];
#pragma unroll
    for (int p = 0; p < 5; ++p) {
        const int c = tid + p * 256;
        const int row = c / 272;
        const int rem = c - row * 272;
        const int slot = rem >> 2;
        const int clog = (rem & 3) ^ ((slot >> 1) & 3);
        const int z = slot - 2;
        srow[p] = row;
        szok[p] = ((unsigned)z < 64u);
        soff[p] = row * 2048 + z * 32 + clog * 8;
    }

    // Bs staging precompute: 3200 chunks in 13 passes
    int bsrc[13];
#pragma unroll
    for (int k = 0; k < 13; ++k) {
        const int c = tid + k * 256;
        const int tp = c >> 7, rem = c & 127;
        const int dxx = tp / 5, dzz = tp - dxx * 5;
        bsrc[k] = (dxx * 25 + dzz) * 128 + rem;
    }

    uint4 R[5];
    auto issue_slab = [&](int dyn, int xln) {
        const int yyb = y0 + dyn - 2;
        const int xx = x0 + xln - 2;
        const bool xok = ((unsigned)xx < 64u);
        const long long xyb =
            (long long)(b * 64 + xx) * 131072 + (long long)yyb * 2048;
#pragma unroll
        for (int p = 0; p < 4; ++p) {
            const int yy = yyb + srow[p];
            const bool ok = xok && ((unsigned)yy < 64u) && szok[p];
            const unsigned short* src = ok ? (xt + xyb + soff[p]) : zpage;
            R[p] = *reinterpret_cast<const uint4*>(src);
        }
        if (tid < 64) {
            const int yy = yyb + srow[4];
            const bool ok = xok && ((unsigned)yy < 64u) && szok[4];
            const unsigned short* src = ok ? (xt + xyb + soff[4]) : zpage;
            R[4] = *reinterpret_cast<const uint4*>(src);
        }
    };

    f32x16 acc[2][4];
#pragma unroll
    for (int oyi = 0; oyi < 2; ++oyi)
#pragma unroll
        for (int ox = 0; ox < 4; ++ox)
#pragma unroll
            for (int e = 0; e < 16; ++e) acc[oyi][ox][e] = 0.0f;

    // prologue: loads for step (dy=0, xl=0)
    issue_slab(0, 0);

    for (int dy = 0; dy < 5; ++dy) {
#pragma unroll
        for (int xl = 0; xl < 8; ++xl) {
            // ---- barrier 1: everyone done READING slab/Bs of prev step
            asm volatile("s_waitcnt lgkmcnt(0)" ::: "memory");
            __builtin_amdgcn_s_barrier();
            __builtin_amdgcn_sched_barrier(0);

            // commit prefetched slab regs -> LDS (auto vmcnt wait on R)
#pragma unroll
            for (int p = 0; p < 4; ++p)
                *reinterpret_cast<uint4*>(
                    lds + 51200 + (tid + p * 256) * 16) = R[p];
            if (tid < 64)
                *reinterpret_cast<uint4*>(
                    lds + 51200 + (tid + 1024) * 16) = R[4];

            if (xl == 0) {
                // stage Bs(dy): 3200 chunks via global_load_lds
#pragma unroll
                for (int k = 0; k < 13; ++k) {
                    const int c0 = wv * 64 + k * 256;
                    if (c0 < 3200) {
                        gld_lds16(kwb + ((size_t)(bsrc[k] + dy * 640)) * 8,
                                  lds + c0 * 16);
                    }
                }
                // keep Bs loads OLDER than the slab prefetch (vmcnt count)
                __builtin_amdgcn_sched_barrier(0);
            }

            // prefetch next step's slab into regs (stays in flight
            // across the barrier and the whole compute step)
            if (!(dy == 4 && xl == 7)) {
                issue_slab(xl == 7 ? dy + 1 : dy, xl == 7 ? 0 : xl + 1);
            }

            // ---- barrier 2: slab writes visible; Bs staged (counted wait)
            asm volatile("s_waitcnt lgkmcnt(0)" ::: "memory");
            if (xl == 0) {
                if (wv == 0)
                    asm volatile("s_waitcnt vmcnt(5)" ::: "memory");
                else
                    asm volatile("s_waitcnt vmcnt(4)" ::: "memory");
            }
            __builtin_amdgcn_s_barrier();
            __builtin_amdgcn_sched_barrier(0);

            // compute: per (dz,kh): 2 A-reads (oy pair), B shared across oy
#pragma unroll
            for (int dz = 0; dz < 5; ++dz) {
#pragma unroll
                for (int kh = 0; kh < 2; ++kh) {
                    const short8 a0 =
                        *reinterpret_cast<const short8*>(lds + abase[dz][kh]);
                    const short8 a1 = *reinterpret_cast<const short8*>(
                        lds + abase[dz][kh] + 4352);
#pragma unroll
                    for (int ox = 0; ox < 4; ++ox) {
                        const int dxv = xl - ox;
                        if (dxv < 0 || dxv > 4) continue;
                        const short8 bf = *reinterpret_cast<const short8*>(
                            lds + bbase + (((dxv * 5 + dz) * 2 + kh) << 10));
                        acc[0][ox] = __builtin_amdgcn_mfma_f32_32x32x16_bf16(
                            a0, bf, acc[0][ox], 0, 0, 0);
                        acc[1][ox] = __builtin_amdgcn_mfma_f32_32x32x16_bf16(
                            a1, bf, acc[1][ox], 0, 0, 0);
                    }
                }
            }
        }
    }

    // epilogue: D lane l: co = l&31, z = zh*32 + rq*8 + (l>>5)*4 + (r&3)
#pragma unroll
    for (int oyi = 0; oyi < 2; ++oyi) {
        const int yy = y0 + oyp * 2 + oyi;
#pragma unroll
        for (int ox = 0; ox < 4; ++ox) {
            float* base = out +
                ((((size_t)b * 32 + l31) * 64 + (x0 + ox)) * 64 + yy) * 64 +
                zh * 32 + hi * 4;
#pragma unroll
            for (int rq = 0; rq < 4; ++rq) {
                f32x4 v = { acc[oyi][ox][rq * 4 + 0], acc[oyi][ox][rq * 4 + 1],
                            acc[oyi][ox][rq * 4 + 2], acc[oyi][ox][rq * 4 + 3] };
                *reinterpret_cast<f32x4*>(base + rq * 8) = v;
            }
        }
    }
}

// ---------------------------------------------------------------------------
extern "C" void kernel_launch(void* const* d_in, const int* in_sizes, int n_in,
                              void* d_out, int out_size, void* d_ws, size_t ws_size,
                              hipStream_t stream) {
    const float* x      = (const float*)d_in[0];
    const float* weight = (const float*)d_in[1];
    const float* w_sc0  = (const float*)d_in[2];
    const float* w_sc1  = (const float*)d_in[3];
    float* out = (float*)d_out;

    char* ws = (char*)d_ws;
    unsigned short* xt  = (unsigned short*)ws;                 // 33,554,432 B
    float*          kwp = (float*)(ws + 33554432);             //    512,000 B
    unsigned short* kwb = (unsigned short*)(ws + 34066432);    //    256,000 B
    unsigned short* zpg = (unsigned short*)(ws + 34322432);    //      4,096 B

    (void)hipFuncSetAttribute((const void*)conv_mfma,
                              hipFuncAttributeMaxDynamicSharedMemorySize,
                              68608);

    hipLaunchKernelGGL(build_kern, dim3(NTAP), dim3(128), 0, stream,
                       weight, w_sc0, w_sc1, kwp);
    hipLaunchKernelGGL(pack_b, dim3(NTAP), dim3(128), 0, stream, kwp, kwb);
    hipLaunchKernelGGL(xpose, dim3(64, 64, 2), dim3(256), 0, stream, x, xt);
    hipLaunchKernelGGL(zero_fill, dim3(1), dim3(256), 0, stream, (float4*)zpg);
    hipLaunchKernelGGL(conv_mfma, dim3(16, 16, 2), dim3(256), 68608, stream,
                       xt, kwb, zpg, out);
}

// Round 3
// 147.409 us; speedup vs baseline: 1.3471x; 1.3471x over previous
//
#include <hip/hip_runtime.h>
#include <math.h>

typedef __attribute__((ext_vector_type(8))) short short8;
typedef __attribute__((ext_vector_type(4))) float f32x4;
typedef __attribute__((ext_vector_type(16))) float f32x16;

#define NTAP 125
#define DCH 32

static __device__ __forceinline__ unsigned short f2bf(float f) {
    union { float f; unsigned u; } v; v.f = f;
    unsigned u = v.u;
    return (unsigned short)((u + 0x7FFFu + ((u >> 16) & 1u)) >> 16);
}

static __device__ __forceinline__ void gld_lds16(const void* g, void* l) {
    __builtin_amdgcn_global_load_lds(
        (const __attribute__((address_space(1))) unsigned int*)g,
        (__attribute__((address_space(3))) unsigned int*)l, 16, 0, 0);
}

// ---------------------------------------------------------------------------
// Kernel 1: build conv weights kw[ci=32][tap=125][co=32] (fp32).
// Skip connection folded into center tap 62. (verified R0-R3)
// ---------------------------------------------------------------------------
__global__ __launch_bounds__(128) void build_kern(
    const float* __restrict__ weight,
    const float* __restrict__ w_sc0,
    const float* __restrict__ w_sc1,
    float* __restrict__ kw)
{
    const int t = blockIdx.x;
    const int dx = t / 25, dy = (t / 5) % 5, dz = t % 5;
    const float px = dx - 2.0f, py = dy - 2.0f, pz = dz - 2.0f;
    const float d = sqrtf(px * px + py * py + pz * pz);

    const float stepv = 2.5f / 6.0f;
    const float embc = 1.14136f * expf(2.0f);
    float emb[5];
#pragma unroll
    for (int n = 0; n < 5; ++n) {
        float diff = (d - stepv * (float)(n + 1)) / stepv;
        float a = diff + 1.0f, bb = 1.0f - diff;
        float v = 0.0f;
        if (a > 0.0f && bb > 0.0f)
            v = embc * expf(-1.0f / a) * expf(-1.0f / bb);
        emb[n] = v;
    }

    const float inv_d = (d > 0.0f) ? 1.0f / d : 0.0f;
    const float ux = px * inv_d, uy = py * inv_d, uz = pz * inv_d;
    const float s3 = 1.73205081f, s5 = 2.23606798f, s15 = 3.87298335f;
    float sh[9];
    sh[0] = 1.0f;
    sh[1] = s3 * ux; sh[2] = s3 * uy; sh[3] = s3 * uz;
    sh[4] = s15 * ux * uz;
    sh[5] = s15 * ux * uy;
    sh[6] = s5 * (uy * uy - 0.5f * (ux * ux + uz * uz));
    sh[7] = s15 * uy * uz;
    sh[8] = 0.5f * s15 * (uz * uz - ux * ux);

    const float i_s2 = 0.70710678f, i_s6 = 0.40824829f, i_s5 = 0.44721360f;
    float T[3][3];
    T[0][0] = i_s5 * (-sh[6] * i_s6 - sh[8] * i_s2);
    T[0][1] = i_s5 * (sh[5] * i_s2);
    T[0][2] = i_s5 * (sh[4] * i_s2);
    T[1][0] = T[0][1];
    T[1][1] = i_s5 * (2.0f * sh[6] * i_s6);
    T[1][2] = i_s5 * (sh[7] * i_s2);
    T[2][0] = T[0][2];
    T[2][1] = T[1][2];
    T[2][2] = i_s5 * (-sh[6] * i_s6 + sh[8] * i_s2);

    __shared__ float Wt[320];
    for (int col = threadIdx.x; col < 320; col += 128) {
        float a = 0.0f;
#pragma unroll
        for (int n = 0; n < 5; ++n) a += emb[n] * weight[n * 320 + col];
        Wt[col] = a * (1.0f / 125.0f);
    }
    __syncthreads();

    const float pw0 = 0.25f;
    const float pw1 = 0.35355339f;
    const float inv_s3 = 0.57735027f;
    const float inv_s8 = 0.35355339f;

    for (int idx = threadIdx.x; idx < 1024; idx += 128) {
        const int o = idx >> 5, i = idx & 31;
        float val;
        if (o < 8) {
            if (i < 8) {
                val = pw0 * Wt[i * 8 + o];
            } else {
                const int u = (i - 8) / 3, m = (i - 8) % 3;
                val = pw0 * inv_s3 * Wt[192 + u * 8 + o] * sh[1 + m];
            }
        } else {
            const int v = (o - 8) / 3, k = (o - 8) % 3;
            if (i < 8) {
                val = pw1 * inv_s3 * Wt[64 + i * 8 + v] * sh[1 + k];
            } else {
                const int u = (i - 8) / 3, m = (i - 8) % 3;
                float tv = Wt[256 + u * 8 + v] * T[m][k];
                if (m == k) tv += inv_s3 * Wt[128 + u * 8 + v];
                val = pw1 * tv;
            }
        }
        if (t == 62) {
            if (o < 8 && i < 8) {
                val += inv_s8 * w_sc0[i * 8 + o];
            } else if (o >= 8 && i >= 8) {
                const int u = (i - 8) / 3, m = (i - 8) % 3;
                const int v = (o - 8) / 3, k = (o - 8) % 3;
                if (m == k) val += inv_s8 * w_sc1[u * 8 + v];
            }
        }
        kw[(i * NTAP + t) * DCH + o] = val;
    }
}

// ---------------------------------------------------------------------------
// Kernel 2: pack kw -> bf16 B-fragments for mfma_f32_32x32x16_bf16.
// kwb[tap][kh][lane][8]: lane l holds B[k=(l>>5)*8+j][n=l&31],
// ci = kh*16 + (l>>5)*8 + j, co = l&31.
// ---------------------------------------------------------------------------
__global__ __launch_bounds__(128) void pack_b(
    const float* __restrict__ kw, unsigned short* __restrict__ kwb)
{
    const int t = blockIdx.x;
    const int tid = threadIdx.x;
    const int kh = tid >> 6, l = tid & 63;
    const int co = l & 31;
    const int cib = kh * 16 + (l >> 5) * 8;
    unsigned short v[8];
#pragma unroll
    for (int j = 0; j < 8; ++j)
        v[j] = f2bf(kw[((cib + j) * NTAP + t) * DCH + co]);
    uint4 o;
    o.x = (unsigned)v[0] | ((unsigned)v[1] << 16);
    o.y = (unsigned)v[2] | ((unsigned)v[3] << 16);
    o.z = (unsigned)v[4] | ((unsigned)v[5] << 16);
    o.w = (unsigned)v[6] | ((unsigned)v[7] << 16);
    *reinterpret_cast<uint4*>(kwb + ((size_t)(t * 2 + kh) * 64 + l) * 8) = o;
}

// ---------------------------------------------------------------------------
// Kernel 3: transpose x fp32 [b][ci][X][Y][Z] -> bf16 x_t[b][X][Y][Z][ci=32]
// ---------------------------------------------------------------------------
__global__ __launch_bounds__(256) void xpose(
    const float* __restrict__ x, unsigned short* __restrict__ xt)
{
    const int xx = blockIdx.x, yy = blockIdx.y, b = blockIdx.z;
    const int t = threadIdx.x;
    const int z = t & 63, part = t >> 6;
    const float* src = x + ((((size_t)b * 32) * 64 + xx) * 64 + yy) * 64 + z;
    unsigned short v[8];
#pragma unroll
    for (int j = 0; j < 8; ++j)
        v[j] = f2bf(src[(size_t)(part * 8 + j) * 262144]);
    uint4 o;
    o.x = (unsigned)v[0] | ((unsigned)v[1] << 16);
    o.y = (unsigned)v[2] | ((unsigned)v[3] << 16);
    o.z = (unsigned)v[4] | ((unsigned)v[5] << 16);
    o.w = (unsigned)v[6] | ((unsigned)v[7] << 16);
    *reinterpret_cast<uint4*>(
        xt + ((((size_t)b * 64 + xx) * 64 + yy) * 64 + z) * 32 + part * 8) = o;
}

__global__ void zero_fill(float4* p) {
    p[threadIdx.x] = make_float4(0.f, 0.f, 0.f, 0.f);
}

// ---------------------------------------------------------------------------
// Kernel 4: implicit-GEMM conv via mfma_f32_32x32x16_bf16.
// R3: 2-phase double-buffered schedule (catalog T3 minimum form), staging
// back on global_load_lds (R2's reg-staged commit was a regression).
// Block 512 thr (8 waves), tile 4x*8y*64z, grid 16*8*2 = 256 = 1 block/CU.
// Wave wv: zh = wv&1, oy pair = (wv>>1)*2 + {0,1}; 8 acc (4ox x 2oy).
// LDS 120832 B: Bs[25][2][64][16B] (51200, single) +
// slab dbuf 2 x [8 row][68 slot][4 chunk][16B] (2 x 34816).
// Schedule per step (dy,xl): TOP: issue gld_lds for NEXT step's slab into
// buf[(xl&1)^1]; compute from buf[xl&1]; __syncthreads() at END. The
// syncthreads' vmcnt(0) drains loads issued a full compute phase earlier
// -> near-free (R1 issued staging right before the consuming barrier ->
// full latency exposed -> the 43% MfmaUtil ceiling).
// Bs restaged at (dy,0) top behind a counted vmcnt mid-barrier: Bs issued
// BEFORE slab prefetch, then vmcnt(5|4) retires Bs, keeps slab in flight.
// Buffer parity compile-time: 8 steps/dy -> buf = xl&1; offsets fold into
// ds_read immediates (zero addr VALU in inner loop).
// ---------------------------------------------------------------------------
__global__ __launch_bounds__(512, 2) void conv_mfma(
    const unsigned short* __restrict__ xt,   // [b][64][64][64][32] bf16
    const unsigned short* __restrict__ kwb,  // [125][2][64][8]
    const unsigned short* __restrict__ zpage,
    float* __restrict__ out)                 // [b][32][64][64][64]
{
    extern __shared__ unsigned short smem[];
    char* lds = (char*)smem;

    const int tid = threadIdx.x;
    const int lane = tid & 63;
    const int wv = tid >> 6;                 // 0..7
    const int oyp = wv >> 1, zh = wv & 1;    // oy pair 0..3, z half
    const int x0 = blockIdx.x * 4, y0 = blockIdx.y * 8;
    const int b = blockIdx.z;
    const int l31 = lane & 31, hi = lane >> 5;

    // A-read base (slab buf0, oyi=0); oyi=1: +4352, buf1: +34816 (imm-folded)
    int abase[5][2];
#pragma unroll
    for (int dz = 0; dz < 5; ++dz) {
        const int s = zh * 32 + l31 + dz;
#pragma unroll
        for (int kh = 0; kh < 2; ++kh) {
            const int cph = (kh * 2 + hi) ^ ((s >> 1) & 3);
            abase[dz][kh] =
                51200 + ((((oyp * 2 * 68 + s) << 2) | cph) << 4);
        }
    }
    const int bbase = lane * 16;

    // slab staging precompute: 2176 chunks, c = tid + p*512
    // (p<4 all threads; p==4 only waves 0-1)
    int srow[5]; int soff[5]; bool szok[5];
#pragma unroll
    for (int p = 0; p < 5; ++p) {
        const int c = tid + p * 512;
        const int row = c / 272;
        const int rem = c - row * 272;
        const int slot = rem >> 2;
        const int clog = (rem & 3) ^ ((slot >> 1) & 3);
        const int z = slot - 2;
        srow[p] = row;
        szok[p] = ((unsigned)z < 64u);
        soff[p] = row * 2048 + z * 32 + clog * 8;
    }

    // Bs staging precompute: 3200 chunks, c = tid + k*512
    int bsrc[7];
#pragma unroll
    for (int k = 0; k < 7; ++k) {
        const int c = tid + k * 512;
        const int tp = c >> 7, rem = c & 127;
        const int dxx = tp / 5, dzz = tp - dxx * 5;
        bsrc[k] = (dxx * 25 + dzz) * 128 + rem;
    }

    auto issue_bs = [&](int dy) {
#pragma unroll
        for (int k = 0; k < 7; ++k) {
            const int c0 = wv * 64 + k * 512;   // wave-uniform dest base
            if (c0 < 3200) {
                gld_lds16(kwb + ((size_t)(bsrc[k] + dy * 640)) * 8,
                          lds + c0 * 16);
            }
        }
    };

    auto issue_slab = [&](int dyn, int xln, int bufi) {
        const int yyb = y0 + dyn - 2;
        const int xx = x0 + xln - 2;
        const bool xok = ((unsigned)xx < 64u);
        const long long xyb =
            (long long)(b * 64 + xx) * 131072 + (long long)yyb * 2048;
        char* dst = lds + 51200 + bufi * 34816;
#pragma unroll
        for (int p = 0; p < 4; ++p) {
            const int yy = yyb + srow[p];
            const bool ok = xok && ((unsigned)yy < 64u) && szok[p];
            const unsigned short* src = ok ? (xt + xyb + soff[p]) : zpage;
            gld_lds16(src, dst + (wv * 64 + p * 512) * 16);
        }
        if (wv < 2) {   // chunks 2048..2175
            const int yy = yyb + srow[4];
            const bool ok = xok && ((unsigned)yy < 64u) && szok[4];
            const unsigned short* src = ok ? (xt + xyb + soff[4]) : zpage;
            gld_lds16(src, dst + (wv * 64 + 2048) * 16);
        }
    };

    f32x16 acc[2][4];
#pragma unroll
    for (int oyi = 0; oyi < 2; ++oyi)
#pragma unroll
        for (int ox = 0; ox < 4; ++ox)
#pragma unroll
            for (int e = 0; e < 16; ++e) acc[oyi][ox][e] = 0.0f;

    // prologue: Bs(0) + slab(0,0) -> buf0, full drain
    issue_bs(0);
    issue_slab(0, 0, 0);
    __syncthreads();

    for (int dy = 0; dy < 5; ++dy) {
#pragma unroll
        for (int xl = 0; xl < 8; ++xl) {
            if (xl == 0) {
                if (dy > 0) {
                    // restage Bs(dy) (prev readers done at last syncthreads)
                    issue_bs(dy);
                    __builtin_amdgcn_sched_barrier(0);
                    // prefetch slab(dy,1) -> buf1 (stays in flight)
                    issue_slab(dy, 1, 1);
                    __builtin_amdgcn_sched_barrier(0);
                    // counted wait: retire Bs, keep slab prefetch in flight
                    if (wv < 2)
                        asm volatile("s_waitcnt vmcnt(5)" ::: "memory");
                    else
                        asm volatile("s_waitcnt vmcnt(4)" ::: "memory");
                    __builtin_amdgcn_s_barrier();
                    __builtin_amdgcn_sched_barrier(0);
                } else {
                    // dy==0: Bs(0)+slab(0,0) visible from prologue barrier
                    issue_slab(0, 1, 1);
                }
            } else if (!(dy == 4 && xl == 7)) {
                // prefetch next step's slab into the other buffer
                issue_slab(xl == 7 ? dy + 1 : dy, xl == 7 ? 0 : xl + 1,
                           (xl & 1) ^ 1);
            }

            // compute from buf[xl&1] (boff is a compile-time immediate)
            const int boff = (xl & 1) * 34816;
#pragma unroll
            for (int dz = 0; dz < 5; ++dz) {
#pragma unroll
                for (int kh = 0; kh < 2; ++kh) {
                    const short8 a0 = *reinterpret_cast<const short8*>(
                        lds + abase[dz][kh] + boff);
                    const short8 a1 = *reinterpret_cast<const short8*>(
                        lds + abase[dz][kh] + boff + 4352);
#pragma unroll
                    for (int ox = 0; ox < 4; ++ox) {
                        const int dxv = xl - ox;
                        if (dxv < 0 || dxv > 4) continue;
                        const short8 bf = *reinterpret_cast<const short8*>(
                            lds + bbase + (((dxv * 5 + dz) * 2 + kh) << 10));
                        acc[0][ox] = __builtin_amdgcn_mfma_f32_32x32x16_bf16(
                            a0, bf, acc[0][ox], 0, 0, 0);
                        acc[1][ox] = __builtin_amdgcn_mfma_f32_32x32x16_bf16(
                            a1, bf, acc[1][ox], 0, 0, 0);
                    }
                }
            }
            // END barrier: drains this step's prefetch (hidden by compute)
            __syncthreads();
        }
    }

    // epilogue: D lane l: co = l&31, z = zh*32 + rq*8 + (l>>5)*4 + (r&3)
#pragma unroll
    for (int oyi = 0; oyi < 2; ++oyi) {
        const int yy = y0 + oyp * 2 + oyi;
#pragma unroll
        for (int ox = 0; ox < 4; ++ox) {
            float* base = out +
                ((((size_t)b * 32 + l31) * 64 + (x0 + ox)) * 64 + yy) * 64 +
                zh * 32 + hi * 4;
#pragma unroll
            for (int rq = 0; rq < 4; ++rq) {
                f32x4 v = { acc[oyi][ox][rq * 4 + 0], acc[oyi][ox][rq * 4 + 1],
                            acc[oyi][ox][rq * 4 + 2], acc[oyi][ox][rq * 4 + 3] };
                *reinterpret_cast<f32x4*>(base + rq * 8) = v;
            }
        }
    }
}

// ---------------------------------------------------------------------------
extern "C" void kernel_launch(void* const* d_in, const int* in_sizes, int n_in,
                              void* d_out, int out_size, void* d_ws, size_t ws_size,
                              hipStream_t stream) {
    const float* x      = (const float*)d_in[0];
    const float* weight = (const float*)d_in[1];
    const float* w_sc0  = (const float*)d_in[2];
    const float* w_sc1  = (const float*)d_in[3];
    float* out = (float*)d_out;

    char* ws = (char*)d_ws;
    unsigned short* xt  = (unsigned short*)ws;                 // 33,554,432 B
    float*          kwp = (float*)(ws + 33554432);             //    512,000 B
    unsigned short* kwb = (unsigned short*)(ws + 34066432);    //    256,000 B
    unsigned short* zpg = (unsigned short*)(ws + 34322432);    //      4,096 B

    (void)hipFuncSetAttribute((const void*)conv_mfma,
                              hipFuncAttributeMaxDynamicSharedMemorySize,
                              120832);

    hipLaunchKernelGGL(build_kern, dim3(NTAP), dim3(128), 0, stream,
                       weight, w_sc0, w_sc1, kwp);
    hipLaunchKernelGGL(pack_b, dim3(NTAP), dim3(128), 0, stream, kwp, kwb);
    hipLaunchKernelGGL(xpose, dim3(64, 64, 2), dim3(256), 0, stream, x, xt);
    hipLaunchKernelGGL(zero_fill, dim3(1), dim3(256), 0, stream, (float4*)zpg);
    hipLaunchKernelGGL(conv_mfma, dim3(16, 8, 2), dim3(512), 120832, stream,
                       xt, kwb, zpg, out);
}